// Round 1
// baseline (536.687 us; speedup 1.0000x reference)
//
#include <hip/hip_runtime.h>

#define NPIX 786432
#define KNB 9
#define CIN 16
#define COUT 16

// One thread per pixel n; each thread computes all 16 output channels for
// BOTH batches (shared neighbour indices). Gathers are 4x float4 per row.
// Pad row (idx==NPIX) handled branchlessly: clamp row to 0, scale by 0.0f.
// w accesses are wave-uniform constant offsets -> scalar loads, so the inner
// loop is v_fma_f32 with an SGPR weight operand.
__global__ __launch_bounds__(256) void healpix_conv_kernel(
    const float* __restrict__ x,
    const int* __restrict__ neigh,
    const float* __restrict__ w,
    const float* __restrict__ bias,
    float* __restrict__ out)
{
    const int n = blockIdx.x * 256 + threadIdx.x;
    if (n >= NPIX) return;

    float acc0[COUT];
    float acc1[COUT];
#pragma unroll
    for (int o = 0; o < COUT; ++o) {
        const float bv = bias[o];
        acc0[o] = bv;
        acc1[o] = bv;
    }

    // Load the 9 neighbour indices up front.
    int idx[KNB];
#pragma unroll
    for (int k = 0; k < KNB; ++k) idx[k] = neigh[n * KNB + k];

    const float* __restrict__ xb1 = x + (size_t)NPIX * CIN;  // batch 1 base

    for (int k = 0; k < KNB; ++k) {  // rolled: keeps code ~4KB, icache-friendly
        const int id = idx[k];
        const int row = (id < NPIX) ? id : 0;
        const float m = (id < NPIX) ? 1.0f : 0.0f;

        const float4* __restrict__ r0 = (const float4*)(x   + (size_t)row * CIN);
        const float4* __restrict__ r1 = (const float4*)(xb1 + (size_t)row * CIN);
        const float4 v0 = r0[0], v1 = r0[1], v2 = r0[2], v3 = r0[3];
        const float4 u0 = r1[0], u1 = r1[1], u2 = r1[2], u3 = r1[3];

        float xa[CIN], xbv[CIN];
        xa[0]  = v0.x * m; xa[1]  = v0.y * m; xa[2]  = v0.z * m; xa[3]  = v0.w * m;
        xa[4]  = v1.x * m; xa[5]  = v1.y * m; xa[6]  = v1.z * m; xa[7]  = v1.w * m;
        xa[8]  = v2.x * m; xa[9]  = v2.y * m; xa[10] = v2.z * m; xa[11] = v2.w * m;
        xa[12] = v3.x * m; xa[13] = v3.y * m; xa[14] = v3.z * m; xa[15] = v3.w * m;
        xbv[0]  = u0.x * m; xbv[1]  = u0.y * m; xbv[2]  = u0.z * m; xbv[3]  = u0.w * m;
        xbv[4]  = u1.x * m; xbv[5]  = u1.y * m; xbv[6]  = u1.z * m; xbv[7]  = u1.w * m;
        xbv[8]  = u2.x * m; xbv[9]  = u2.y * m; xbv[10] = u2.z * m; xbv[11] = u2.w * m;
        xbv[12] = u3.x * m; xbv[13] = u3.y * m; xbv[14] = u3.z * m; xbv[15] = u3.w * m;

        // w[o][k][c] at w[o*KNB*CIN + k*CIN + c]; o,k,c wave-uniform -> s_load
        const float* __restrict__ wk = w + k * CIN;
#pragma unroll
        for (int o = 0; o < COUT; ++o) {
            const float* __restrict__ wo = wk + o * (KNB * CIN);
#pragma unroll
            for (int c = 0; c < CIN; ++c) {
                const float wv = wo[c];
                acc0[o] = fmaf(wv, xa[c],  acc0[o]);
                acc1[o] = fmaf(wv, xbv[c], acc1[o]);
            }
        }
    }

    float* __restrict__ o0 = out + (size_t)n * COUT;
    float* __restrict__ o1 = out + (size_t)NPIX * COUT + (size_t)n * COUT;
    ((float4*)o0)[0] = make_float4(acc0[0],  acc0[1],  acc0[2],  acc0[3]);
    ((float4*)o0)[1] = make_float4(acc0[4],  acc0[5],  acc0[6],  acc0[7]);
    ((float4*)o0)[2] = make_float4(acc0[8],  acc0[9],  acc0[10], acc0[11]);
    ((float4*)o0)[3] = make_float4(acc0[12], acc0[13], acc0[14], acc0[15]);
    ((float4*)o1)[0] = make_float4(acc1[0],  acc1[1],  acc1[2],  acc1[3]);
    ((float4*)o1)[1] = make_float4(acc1[4],  acc1[5],  acc1[6],  acc1[7]);
    ((float4*)o1)[2] = make_float4(acc1[8],  acc1[9],  acc1[10], acc1[11]);
    ((float4*)o1)[3] = make_float4(acc1[12], acc1[13], acc1[14], acc1[15]);
}

extern "C" void kernel_launch(void* const* d_in, const int* in_sizes, int n_in,
                              void* d_out, int out_size, void* d_ws, size_t ws_size,
                              hipStream_t stream) {
    const float* x     = (const float*)d_in[0];
    const int*   neigh = (const int*)d_in[1];
    const float* w     = (const float*)d_in[2];
    const float* bias  = (const float*)d_in[3];
    float* out = (float*)d_out;

    const int blocks = (NPIX + 255) / 256;  // 3072
    healpix_conv_kernel<<<blocks, 256, 0, stream>>>(x, neigh, w, bias, out);
}

// Round 2
// 415.554 us; speedup vs baseline: 1.2915x; 1.2915x over previous
//
#include <hip/hip_runtime.h>
#include <stdint.h>

#define NPIX 786432
#define KNB 9
#define CIN 16
#define COUT 16

// ---------------------------------------------------------------------------
// Pre-pass: convert x (2, NPIX, 16) fp32 -> xw (NPIX+1, 2, 16) bf16 packed as
// 16 uint32 per pixel (batch0's 16 ch then batch1's 16 ch), with an explicit
// ZERO row at p == NPIX (the pad row) so the gather needs no masking at all.
// ---------------------------------------------------------------------------
__device__ __forceinline__ uint32_t bf16_rne(float f) {
    uint32_t u = __float_as_uint(f);
    return (u + 0x7fffu + ((u >> 16) & 1u)) >> 16;
}
__device__ __forceinline__ uint32_t pack2(float lo, float hi) {
    return bf16_rne(lo) | (bf16_rne(hi) << 16);
}

__global__ __launch_bounds__(256) void pack_bf16_kernel(
    const float* __restrict__ x, uint32_t* __restrict__ xw)
{
    const int p = blockIdx.x * 256 + threadIdx.x;
    if (p > NPIX) return;

    uint32_t v[16];
    if (p < NPIX) {
        const float* __restrict__ r0 = x + (size_t)p * CIN;                      // batch 0
        const float* __restrict__ r1 = x + (size_t)NPIX * CIN + (size_t)p * CIN; // batch 1
        const float4 a0 = ((const float4*)r0)[0], a1 = ((const float4*)r0)[1];
        const float4 a2 = ((const float4*)r0)[2], a3 = ((const float4*)r0)[3];
        const float4 b0 = ((const float4*)r1)[0], b1 = ((const float4*)r1)[1];
        const float4 b2 = ((const float4*)r1)[2], b3 = ((const float4*)r1)[3];
        v[0] = pack2(a0.x, a0.y); v[1] = pack2(a0.z, a0.w);
        v[2] = pack2(a1.x, a1.y); v[3] = pack2(a1.z, a1.w);
        v[4] = pack2(a2.x, a2.y); v[5] = pack2(a2.z, a2.w);
        v[6] = pack2(a3.x, a3.y); v[7] = pack2(a3.z, a3.w);
        v[8]  = pack2(b0.x, b0.y); v[9]  = pack2(b0.z, b0.w);
        v[10] = pack2(b1.x, b1.y); v[11] = pack2(b1.z, b1.w);
        v[12] = pack2(b2.x, b2.y); v[13] = pack2(b2.z, b2.w);
        v[14] = pack2(b3.x, b3.y); v[15] = pack2(b3.z, b3.w);
    } else {
#pragma unroll
        for (int i = 0; i < 16; ++i) v[i] = 0u;  // pad row = zeros
    }

    uint4* __restrict__ o = (uint4*)(xw + (size_t)p * 16);
    o[0] = make_uint4(v[0],  v[1],  v[2],  v[3]);
    o[1] = make_uint4(v[4],  v[5],  v[6],  v[7]);
    o[2] = make_uint4(v[8],  v[9],  v[10], v[11]);
    o[3] = make_uint4(v[12], v[13], v[14], v[15]);
}

// ---------------------------------------------------------------------------
// Main: one thread per pixel, both batches. Gather = 64 B/neighbour (4x
// dwordx4, one half-line). 2-stage software pipeline: load row k+1 into the
// alternate register buffer while computing row k. No pad masking (zero row).
// bf16 -> f32 unpack is 1 VALU op per value (shl / and).
// ---------------------------------------------------------------------------
__device__ __forceinline__ float bflo(uint32_t v) { return __uint_as_float(v << 16); }
__device__ __forceinline__ float bfhi(uint32_t v) { return __uint_as_float(v & 0xffff0000u); }

__global__ __launch_bounds__(256) void healpix_conv_kernel(
    const uint32_t* __restrict__ xw,
    const int* __restrict__ neigh,
    const float* __restrict__ w,
    const float* __restrict__ bias,
    float* __restrict__ out)
{
    const int n = blockIdx.x * 256 + threadIdx.x;
    if (n >= NPIX) return;

    int idx[KNB];
#pragma unroll
    for (int k = 0; k < KNB; ++k) idx[k] = neigh[n * KNB + k];

    float acc0[COUT], acc1[COUT];
#pragma unroll
    for (int o = 0; o < COUT; ++o) {
        const float bv = bias[o];
        acc0[o] = bv;
        acc1[o] = bv;
    }

    uint4 buf[2][4];
    {
        const uint4* __restrict__ p = (const uint4*)(xw + (size_t)idx[0] * 16);
        buf[0][0] = p[0]; buf[0][1] = p[1]; buf[0][2] = p[2]; buf[0][3] = p[3];
    }

#pragma unroll
    for (int k = 0; k < KNB; ++k) {
        if (k + 1 < KNB) {
            const uint4* __restrict__ p = (const uint4*)(xw + (size_t)idx[k + 1] * 16);
            const int s = (k + 1) & 1;
            buf[s][0] = p[0]; buf[s][1] = p[1]; buf[s][2] = p[2]; buf[s][3] = p[3];
        }
        const uint4* __restrict__ B = buf[k & 1];

        float xa[CIN], xb[CIN];
        xa[0]  = bflo(B[0].x); xa[1]  = bfhi(B[0].x);
        xa[2]  = bflo(B[0].y); xa[3]  = bfhi(B[0].y);
        xa[4]  = bflo(B[0].z); xa[5]  = bfhi(B[0].z);
        xa[6]  = bflo(B[0].w); xa[7]  = bfhi(B[0].w);
        xa[8]  = bflo(B[1].x); xa[9]  = bfhi(B[1].x);
        xa[10] = bflo(B[1].y); xa[11] = bfhi(B[1].y);
        xa[12] = bflo(B[1].z); xa[13] = bfhi(B[1].z);
        xa[14] = bflo(B[1].w); xa[15] = bfhi(B[1].w);
        xb[0]  = bflo(B[2].x); xb[1]  = bfhi(B[2].x);
        xb[2]  = bflo(B[2].y); xb[3]  = bfhi(B[2].y);
        xb[4]  = bflo(B[2].z); xb[5]  = bfhi(B[2].z);
        xb[6]  = bflo(B[2].w); xb[7]  = bfhi(B[2].w);
        xb[8]  = bflo(B[3].x); xb[9]  = bfhi(B[3].x);
        xb[10] = bflo(B[3].y); xb[11] = bfhi(B[3].y);
        xb[12] = bflo(B[3].z); xb[13] = bfhi(B[3].z);
        xb[14] = bflo(B[3].w); xb[15] = bfhi(B[3].w);

        const float* __restrict__ wk = w + k * CIN;  // w[o][k][c]
#pragma unroll
        for (int o = 0; o < COUT; ++o) {
            const float* __restrict__ wo = wk + o * (KNB * CIN);
#pragma unroll
            for (int c = 0; c < CIN; ++c) {
                const float wv = wo[c];
                acc0[o] = fmaf(wv, xa[c], acc0[o]);
                acc1[o] = fmaf(wv, xb[c], acc1[o]);
            }
        }
    }

    float* __restrict__ o0 = out + (size_t)n * COUT;
    float* __restrict__ o1 = out + (size_t)NPIX * COUT + (size_t)n * COUT;
    ((float4*)o0)[0] = make_float4(acc0[0],  acc0[1],  acc0[2],  acc0[3]);
    ((float4*)o0)[1] = make_float4(acc0[4],  acc0[5],  acc0[6],  acc0[7]);
    ((float4*)o0)[2] = make_float4(acc0[8],  acc0[9],  acc0[10], acc0[11]);
    ((float4*)o0)[3] = make_float4(acc0[12], acc0[13], acc0[14], acc0[15]);
    ((float4*)o1)[0] = make_float4(acc1[0],  acc1[1],  acc1[2],  acc1[3]);
    ((float4*)o1)[1] = make_float4(acc1[4],  acc1[5],  acc1[6],  acc1[7]);
    ((float4*)o1)[2] = make_float4(acc1[8],  acc1[9],  acc1[10], acc1[11]);
    ((float4*)o1)[3] = make_float4(acc1[12], acc1[13], acc1[14], acc1[15]);
}

extern "C" void kernel_launch(void* const* d_in, const int* in_sizes, int n_in,
                              void* d_out, int out_size, void* d_ws, size_t ws_size,
                              hipStream_t stream) {
    const float* x     = (const float*)d_in[0];
    const int*   neigh = (const int*)d_in[1];
    const float* w     = (const float*)d_in[2];
    const float* bias  = (const float*)d_in[3];
    float* out = (float*)d_out;
    uint32_t* xw = (uint32_t*)d_ws;  // (NPIX+1) * 16 u32 = 50.3 MB

    const int pack_blocks = (NPIX + 1 + 255) / 256;  // 3073
    pack_bf16_kernel<<<pack_blocks, 256, 0, stream>>>(x, xw);

    const int conv_blocks = (NPIX + 255) / 256;      // 3072
    healpix_conv_kernel<<<conv_blocks, 256, 0, stream>>>(xw, neigh, w, bias, out);
}

// Round 5
// 335.619 us; speedup vs baseline: 1.5991x; 1.2382x over previous
//
#include <hip/hip_runtime.h>
#include <stdint.h>

#define NPIX 786432
#define KNB 9
#define CIN 16
#define COUT 16
#define NPAIR 8                      // CIN/2
#define WPAIRS (COUT * KNB * NPAIR)  // 1152

typedef _Float16 half2_t __attribute__((ext_vector_type(2)));

__device__ __forceinline__ uint32_t packf16(float lo, float hi) {
    half2_t h;
    h[0] = (_Float16)lo;   // RNE convert
    h[1] = (_Float16)hi;
    return __builtin_bit_cast(uint32_t, h);
}
__device__ __forceinline__ half2_t ash2(uint32_t v) {
    return __builtin_bit_cast(half2_t, v);
}

// ---------------------------------------------------------------------------
// Pre-pass: x (2, NPIX, 16) fp32 -> xw (NPIX+1, 2, 16) f16 packed as 16 u32
// per pixel (batch0's 8 pairs then batch1's 8 pairs), explicit ZERO row at
// p == NPIX. Extra block packs w (16,9,16) fp32 -> 1152 u32 f16 pairs.
// ---------------------------------------------------------------------------
__global__ __launch_bounds__(256) void pack_kernel(
    const float* __restrict__ x, const float* __restrict__ w,
    uint32_t* __restrict__ xw, uint32_t* __restrict__ w2)
{
    const int xblocks = (NPIX + 1 + 255) / 256;  // 3073
    if ((int)blockIdx.x == xblocks) {
        for (int j = threadIdx.x; j < WPAIRS; j += 256)
            w2[j] = packf16(w[2 * j], w[2 * j + 1]);
        return;
    }
    const int p = blockIdx.x * 256 + threadIdx.x;
    if (p > NPIX) return;

    uint32_t v[16];
    if (p < NPIX) {
        const float4* __restrict__ r0 = (const float4*)(x + (size_t)p * CIN);
        const float4* __restrict__ r1 = (const float4*)(x + (size_t)NPIX * CIN + (size_t)p * CIN);
        const float4 a0 = r0[0], a1 = r0[1], a2 = r0[2], a3 = r0[3];
        const float4 b0 = r1[0], b1 = r1[1], b2 = r1[2], b3 = r1[3];
        v[0] = packf16(a0.x, a0.y); v[1] = packf16(a0.z, a0.w);
        v[2] = packf16(a1.x, a1.y); v[3] = packf16(a1.z, a1.w);
        v[4] = packf16(a2.x, a2.y); v[5] = packf16(a2.z, a2.w);
        v[6] = packf16(a3.x, a3.y); v[7] = packf16(a3.z, a3.w);
        v[8]  = packf16(b0.x, b0.y); v[9]  = packf16(b0.z, b0.w);
        v[10] = packf16(b1.x, b1.y); v[11] = packf16(b1.z, b1.w);
        v[12] = packf16(b2.x, b2.y); v[13] = packf16(b2.z, b2.w);
        v[14] = packf16(b3.x, b3.y); v[15] = packf16(b3.z, b3.w);
    } else {
#pragma unroll
        for (int i = 0; i < 16; ++i) v[i] = 0u;  // pad row = zeros
    }

    uint4* __restrict__ o = (uint4*)(xw + (size_t)p * 16);
    o[0] = make_uint4(v[0],  v[1],  v[2],  v[3]);
    o[1] = make_uint4(v[4],  v[5],  v[6],  v[7]);
    o[2] = make_uint4(v[8],  v[9],  v[10], v[11]);
    o[3] = make_uint4(v[12], v[13], v[14], v[15]);
}

// One k-step: 16 output channels x 8 f16-pair dots against row (q0,q1).
__device__ __forceinline__ void conv_step(
    int k, uint4 q0, uint4 q1, const uint32_t* __restrict__ w2, float* acc)
{
    const uint32_t xp[NPAIR] = {q0.x, q0.y, q0.z, q0.w, q1.x, q1.y, q1.z, q1.w};
    const uint32_t* __restrict__ wk = w2 + k * NPAIR;  // w2[o*72 + k*8 + j]
#pragma unroll
    for (int o = 0; o < COUT; ++o) {
        const uint32_t* __restrict__ wo = wk + o * (KNB * NPAIR);
        float a = acc[o];
#pragma unroll
        for (int j = 0; j < NPAIR; ++j)
            a = __builtin_amdgcn_fdot2(ash2(xp[j]), ash2(wo[j]), a, false);
        acc[o] = a;
    }
}

// ---------------------------------------------------------------------------
// Main: one thread per (pixel, batch). Lane pairs (2i,2i+1) share a pixel ->
// their 32 B halves of the same 64 B row coalesce. Explicit 4-deep register
// pipeline (named regs rA..rD, no array index arithmetic). Indices clamped.
// ---------------------------------------------------------------------------
__global__ __launch_bounds__(256) void healpix_conv_kernel(
    const uint32_t* __restrict__ xw,
    const int* __restrict__ neigh,
    const uint32_t* __restrict__ w2,
    const float* __restrict__ bias,
    float* __restrict__ out)
{
    const int t  = blockIdx.x * 256 + threadIdx.x;  // [0, 2*NPIX)
    const int px = t >> 1;
    const int b  = t & 1;

    int idx[KNB];
#pragma unroll
    for (int k = 0; k < KNB; ++k) {
        int id = neigh[px * KNB + k];
        id = id < 0 ? 0 : (id > NPIX ? NPIX : id);  // defensive clamp
        idx[k] = id;
    }

    float acc[COUT];
#pragma unroll
    for (int o = 0; o < COUT; ++o) acc[o] = bias[o];

    const uint32_t* __restrict__ base = xw + b * NPAIR;  // batch half of row

#define ROWPTR(K) ((const uint4*)(base + (size_t)idx[K] * 16))
    uint4 rA0 = ROWPTR(0)[0], rA1 = ROWPTR(0)[1];
    uint4 rB0 = ROWPTR(1)[0], rB1 = ROWPTR(1)[1];
    uint4 rC0 = ROWPTR(2)[0], rC1 = ROWPTR(2)[1];
    uint4 rD0 = ROWPTR(3)[0], rD1 = ROWPTR(3)[1];

    // k=0: consume A, refill A with row 4
    conv_step(0, rA0, rA1, w2, acc);
    rA0 = ROWPTR(4)[0]; rA1 = ROWPTR(4)[1];
    // k=1: consume B, refill B with row 5
    conv_step(1, rB0, rB1, w2, acc);
    rB0 = ROWPTR(5)[0]; rB1 = ROWPTR(5)[1];
    // k=2: consume C, refill C with row 6
    conv_step(2, rC0, rC1, w2, acc);
    rC0 = ROWPTR(6)[0]; rC1 = ROWPTR(6)[1];
    // k=3: consume D, refill D with row 7
    conv_step(3, rD0, rD1, w2, acc);
    rD0 = ROWPTR(7)[0]; rD1 = ROWPTR(7)[1];
    // k=4: consume A, refill A with row 8
    conv_step(4, rA0, rA1, w2, acc);
    rA0 = ROWPTR(8)[0]; rA1 = ROWPTR(8)[1];
    // tail
    conv_step(5, rB0, rB1, w2, acc);
    conv_step(6, rC0, rC1, w2, acc);
    conv_step(7, rD0, rD1, w2, acc);
    conv_step(8, rA0, rA1, w2, acc);
#undef ROWPTR

    float* __restrict__ op = out + (size_t)b * NPIX * COUT + (size_t)px * COUT;
    ((float4*)op)[0] = make_float4(acc[0],  acc[1],  acc[2],  acc[3]);
    ((float4*)op)[1] = make_float4(acc[4],  acc[5],  acc[6],  acc[7]);
    ((float4*)op)[2] = make_float4(acc[8],  acc[9],  acc[10], acc[11]);
    ((float4*)op)[3] = make_float4(acc[12], acc[13], acc[14], acc[15]);
}

extern "C" void kernel_launch(void* const* d_in, const int* in_sizes, int n_in,
                              void* d_out, int out_size, void* d_ws, size_t ws_size,
                              hipStream_t stream) {
    const float* x     = (const float*)d_in[0];
    const int*   neigh = (const int*)d_in[1];
    const float* w     = (const float*)d_in[2];
    const float* bias  = (const float*)d_in[3];
    float* out = (float*)d_out;

    uint32_t* xw = (uint32_t*)d_ws;                      // (NPIX+1)*16 u32 = 50.3 MB
    uint32_t* w2 = xw + (size_t)(NPIX + 1) * 16;         // 1152 u32

    const int xblocks = (NPIX + 1 + 255) / 256;          // 3073
    pack_kernel<<<xblocks + 1, 256, 0, stream>>>(x, w, xw, w2);

    const int conv_blocks = (2 * NPIX) / 256;            // 6144
    healpix_conv_kernel<<<conv_blocks, 256, 0, stream>>>(xw, neigh, w2, bias, out);
}

// Round 6
// 334.724 us; speedup vs baseline: 1.6034x; 1.0027x over previous
//
#include <hip/hip_runtime.h>
#include <stdint.h>

#define NPIX 786432
#define KNB 9
#define CIN 16
#define COUT 16
#define NPAIR 8                      // CIN/2
#define WPAIRS (COUT * KNB * NPAIR)  // 1152

typedef _Float16 half2_t __attribute__((ext_vector_type(2)));

__device__ __forceinline__ uint32_t packf16(float lo, float hi) {
    half2_t h;
    h[0] = (_Float16)lo;   // RNE convert
    h[1] = (_Float16)hi;
    return __builtin_bit_cast(uint32_t, h);
}
__device__ __forceinline__ half2_t ash2(uint32_t v) {
    return __builtin_bit_cast(half2_t, v);
}

// ---------------------------------------------------------------------------
// Pre-pass: x (2, NPIX, 16) fp32 -> xw (NPIX+1, 2, 16) f16 packed as 16 u32
// per pixel (batch0's 8 pairs then batch1's 8 pairs), explicit ZERO row at
// p == NPIX. Extra block packs w (16,9,16) fp32 -> 1152 u32 f16 pairs.
// ---------------------------------------------------------------------------
__global__ __launch_bounds__(256) void pack_kernel(
    const float* __restrict__ x, const float* __restrict__ w,
    uint32_t* __restrict__ xw, uint32_t* __restrict__ w2)
{
    const int xblocks = (NPIX + 1 + 255) / 256;  // 3073
    if ((int)blockIdx.x == xblocks) {
        for (int j = threadIdx.x; j < WPAIRS; j += 256)
            w2[j] = packf16(w[2 * j], w[2 * j + 1]);
        return;
    }
    const int p = blockIdx.x * 256 + threadIdx.x;
    if (p > NPIX) return;

    uint32_t v[16];
    if (p < NPIX) {
        const float4* __restrict__ r0 = (const float4*)(x + (size_t)p * CIN);
        const float4* __restrict__ r1 = (const float4*)(x + (size_t)NPIX * CIN + (size_t)p * CIN);
        const float4 a0 = r0[0], a1 = r0[1], a2 = r0[2], a3 = r0[3];
        const float4 b0 = r1[0], b1 = r1[1], b2 = r1[2], b3 = r1[3];
        v[0] = packf16(a0.x, a0.y); v[1] = packf16(a0.z, a0.w);
        v[2] = packf16(a1.x, a1.y); v[3] = packf16(a1.z, a1.w);
        v[4] = packf16(a2.x, a2.y); v[5] = packf16(a2.z, a2.w);
        v[6] = packf16(a3.x, a3.y); v[7] = packf16(a3.z, a3.w);
        v[8]  = packf16(b0.x, b0.y); v[9]  = packf16(b0.z, b0.w);
        v[10] = packf16(b1.x, b1.y); v[11] = packf16(b1.z, b1.w);
        v[12] = packf16(b2.x, b2.y); v[13] = packf16(b2.z, b2.w);
        v[14] = packf16(b3.x, b3.y); v[15] = packf16(b3.z, b3.w);
    } else {
#pragma unroll
        for (int i = 0; i < 16; ++i) v[i] = 0u;  // pad row = zeros
    }

    uint4* __restrict__ o = (uint4*)(xw + (size_t)p * 16);
    o[0] = make_uint4(v[0],  v[1],  v[2],  v[3]);
    o[1] = make_uint4(v[4],  v[5],  v[6],  v[7]);
    o[2] = make_uint4(v[8],  v[9],  v[10], v[11]);
    o[3] = make_uint4(v[12], v[13], v[14], v[15]);
}

// One k-step: 16 output channels x 8 f16-pair dots against row (q0,q1).
__device__ __forceinline__ void conv_step(
    int k, uint4 q0, uint4 q1, const uint32_t* __restrict__ w2, float* acc)
{
    const uint32_t xp[NPAIR] = {q0.x, q0.y, q0.z, q0.w, q1.x, q1.y, q1.z, q1.w};
    const uint32_t* __restrict__ wk = w2 + k * NPAIR;  // w2[o*72 + k*8 + j]
#pragma unroll
    for (int o = 0; o < COUT; ++o) {
        const uint32_t* __restrict__ wo = wk + o * (KNB * NPAIR);
        float a = acc[o];
#pragma unroll
        for (int j = 0; j < NPAIR; ++j)
            a = __builtin_amdgcn_fdot2(ash2(xp[j]), ash2(wo[j]), a, false);
        acc[o] = a;
    }
}

// ---------------------------------------------------------------------------
// Main: one thread per (pixel, batch). Lane pairs (2i,2i+1) share a pixel ->
// their 32 B halves of the same 64 B row coalesce. MLP probe: ALL 9 row
// loads issued up front (named registers), then 9 compute steps. 72 buffer
// VGPRs; trades occupancy (~16 waves/CU) for 2.25x in-flight bytes/wave.
// ---------------------------------------------------------------------------
__global__ __launch_bounds__(256) void healpix_conv_kernel(
    const uint32_t* __restrict__ xw,
    const int* __restrict__ neigh,
    const uint32_t* __restrict__ w2,
    const float* __restrict__ bias,
    float* __restrict__ out)
{
    const int t  = blockIdx.x * 256 + threadIdx.x;  // [0, 2*NPIX)
    const int px = t >> 1;
    const int b  = t & 1;

    int idx[KNB];
#pragma unroll
    for (int k = 0; k < KNB; ++k) {
        int id = neigh[px * KNB + k];
        id = id < 0 ? 0 : (id > NPIX ? NPIX : id);  // defensive clamp
        idx[k] = id;
    }

    const uint32_t* __restrict__ base = xw + b * NPAIR;  // batch half of row

#define ROWPTR(K) ((const uint4*)(base + (size_t)idx[K] * 16))
    // All 9 gathers in flight before any compute.
    const uint4 r0a = ROWPTR(0)[0], r0b = ROWPTR(0)[1];
    const uint4 r1a = ROWPTR(1)[0], r1b = ROWPTR(1)[1];
    const uint4 r2a = ROWPTR(2)[0], r2b = ROWPTR(2)[1];
    const uint4 r3a = ROWPTR(3)[0], r3b = ROWPTR(3)[1];
    const uint4 r4a = ROWPTR(4)[0], r4b = ROWPTR(4)[1];
    const uint4 r5a = ROWPTR(5)[0], r5b = ROWPTR(5)[1];
    const uint4 r6a = ROWPTR(6)[0], r6b = ROWPTR(6)[1];
    const uint4 r7a = ROWPTR(7)[0], r7b = ROWPTR(7)[1];
    const uint4 r8a = ROWPTR(8)[0], r8b = ROWPTR(8)[1];
#undef ROWPTR

    float acc[COUT];
#pragma unroll
    for (int o = 0; o < COUT; ++o) acc[o] = bias[o];

    conv_step(0, r0a, r0b, w2, acc);
    conv_step(1, r1a, r1b, w2, acc);
    conv_step(2, r2a, r2b, w2, acc);
    conv_step(3, r3a, r3b, w2, acc);
    conv_step(4, r4a, r4b, w2, acc);
    conv_step(5, r5a, r5b, w2, acc);
    conv_step(6, r6a, r6b, w2, acc);
    conv_step(7, r7a, r7b, w2, acc);
    conv_step(8, r8a, r8b, w2, acc);

    float* __restrict__ op = out + (size_t)b * NPIX * COUT + (size_t)px * COUT;
    ((float4*)op)[0] = make_float4(acc[0],  acc[1],  acc[2],  acc[3]);
    ((float4*)op)[1] = make_float4(acc[4],  acc[5],  acc[6],  acc[7]);
    ((float4*)op)[2] = make_float4(acc[8],  acc[9],  acc[10], acc[11]);
    ((float4*)op)[3] = make_float4(acc[12], acc[13], acc[14], acc[15]);
}

extern "C" void kernel_launch(void* const* d_in, const int* in_sizes, int n_in,
                              void* d_out, int out_size, void* d_ws, size_t ws_size,
                              hipStream_t stream) {
    const float* x     = (const float*)d_in[0];
    const int*   neigh = (const int*)d_in[1];
    const float* w     = (const float*)d_in[2];
    const float* bias  = (const float*)d_in[3];
    float* out = (float*)d_out;

    uint32_t* xw = (uint32_t*)d_ws;                      // (NPIX+1)*16 u32 = 50.3 MB
    uint32_t* w2 = xw + (size_t)(NPIX + 1) * 16;         // 1152 u32

    const int xblocks = (NPIX + 1 + 255) / 256;          // 3073
    pack_kernel<<<xblocks + 1, 256, 0, stream>>>(x, w, xw, w2);

    const int conv_blocks = (2 * NPIX) / 256;            // 6144
    healpix_conv_kernel<<<conv_blocks, 256, 0, stream>>>(xw, neigh, w2, bias, out);
}